// Round 1
// baseline (126.851 us; speedup 1.0000x reference)
//
#include <hip/hip_runtime.h>
#include <hip/hip_bf16.h>
#include <hip/hip_fp16.h>

#define N_BCH 8
#define N_ATM 10000
#define N_ELM 100
#define N_ATOMS_TOT 80000

typedef int   i4 __attribute__((ext_vector_type(4)));
typedef float f4 __attribute__((ext_vector_type(4)));

// R5: no-workspace variant. Packing of elm (int32 -> u8) is fused into the
// LDS staging pass of edge_kernel; pack_elm_kernel and d_ws are gone.
// Purpose: (1) drop one dispatch from the timed graph, (2) test whether the
// two 256-MiB fillBuffer dispatches in the timed window are workspace
// poisoning (if so they disappear -> -40..-81 us).
//
// R4 champion structure otherwise unchanged:
//   s_elm32 : 80000 B u8 element types (whole batch), packed in-kernel
//   s_kr    : 100x half2(k,r) -> one ds_read_b32 per endpoint
// LDS ~79.1 KiB -> 2 blocks/CU x 1024 thr = 32 waves/CU.
__launch_bounds__(1024, 8)
__global__ void edge_kernel(const int* __restrict__ elm,
                            const float* __restrict__ kparam,
                            const float* __restrict__ radius,
                            const int* __restrict__ edge_n,
                            const int* __restrict__ edge_i,
                            const int* __restrict__ edge_j,
                            const float* __restrict__ sod,
                            float* __restrict__ out,
                            int nE) {
    __shared__ unsigned int s_elm32[N_ATOMS_TOT / 4];  // 80000 B
    __shared__ __half2 s_kr[128];                      // 512 B (100 used)
    __shared__ float s_red[16][N_BCH];                 // 512 B

    // ---- stage elm table: read int32 elm (i4 = 4 atoms / 16B), pack to u8 ----
    {
        const i4* src = (const i4*)elm;
        for (int t = threadIdx.x; t < N_ATOMS_TOT / 4; t += 1024) {
            i4 v = src[t];
            s_elm32[t] = (unsigned int)(v[0] & 0xff)
                       | ((unsigned int)(v[1] & 0xff) << 8)
                       | ((unsigned int)(v[2] & 0xff) << 16)
                       | ((unsigned int)(v[3] & 0xff) << 24);
        }
        if (threadIdx.x < N_ELM)
            s_kr[threadIdx.x] =
                __floats2half2_rn(kparam[threadIdx.x], radius[threadIdx.x]);
    }
    __syncthreads();

    const unsigned char* s_elm = (const unsigned char*)s_elm32;

    float acc[N_BCH];
#pragma unroll
    for (int b = 0; b < N_BCH; ++b) acc[b] = 0.0f;

    const int tid    = blockIdx.x * blockDim.x + threadIdx.x;
    const int stride = gridDim.x * blockDim.x;
    const int nvec   = nE >> 2;

    const i4* en4 = (const i4*)edge_n;
    const i4* ei4 = (const i4*)edge_i;
    const i4* ej4 = (const i4*)edge_j;
    const f4* s4  = (const f4*)sod;

    for (int v = tid; v < nvec; v += stride) {
        i4 nn = en4[v];         // plain loads: let L3-resident input serve hits
        i4 ii = ei4[v];
        i4 jj = ej4[v];
        f4 ss = s4[v];

#pragma unroll
        for (int u = 0; u < 4; ++u) {
            int n = nn[u];
            int base = n * N_ATM;
            int e_i = s_elm[base + ii[u]];
            int e_j = s_elm[base + jj[u]];
            __half2 krsum = __hadd2(s_kr[e_i], s_kr[e_j]);
            float kk = __low2float(krsum);
            float R  = __high2float(krsum);
            float dis = sqrtf(ss[u]);
            float d   = fminf(dis - R, 0.0f);   // ==0 unless dis<R (exact)
            float val = kk * d * d;
#pragma unroll
            for (int b = 0; b < N_BCH; ++b)
                acc[b] += (n == b) ? val : 0.0f;
        }
    }

    // scalar tail (nE % 4)
    const int tail_start = nvec << 2;
    const int tail_n = nE - tail_start;
    if (tid < tail_n) {
        int e = tail_start + tid;
        int n = edge_n[e];
        int e_i = s_elm[n * N_ATM + edge_i[e]];
        int e_j = s_elm[n * N_ATM + edge_j[e]];
        __half2 krsum = __hadd2(s_kr[e_i], s_kr[e_j]);
        float kk = __low2float(krsum);
        float R  = __high2float(krsum);
        float dis = sqrtf(sod[e]);
        float d   = fminf(dis - R, 0.0f);
        float val = kk * d * d;
#pragma unroll
        for (int b = 0; b < N_BCH; ++b)
            acc[b] += (n == b) ? val : 0.0f;
    }

    // ---- two-phase wave reduction ----
    const int lane = threadIdx.x & 63;
    const int wave = threadIdx.x >> 6;   // 16 waves
#pragma unroll
    for (int off = 8; off <= 32; off <<= 1) {
#pragma unroll
        for (int b = 0; b < N_BCH; ++b)
            acc[b] += __shfl_xor(acc[b], off, 64);
    }
    const int j = lane >> 3;
    float x = acc[0];
#pragma unroll
    for (int b = 1; b < N_BCH; ++b) x = (j == b) ? acc[b] : x;
#pragma unroll
    for (int off = 1; off <= 4; off <<= 1)
        x += __shfl_xor(x, off, 64);

    if ((lane & 7) == 0) s_red[wave][j] = x;
    __syncthreads();
    if (threadIdx.x < N_BCH) {
        float t = 0.0f;
#pragma unroll
        for (int w = 0; w < 16; ++w) t += s_red[w][threadIdx.x];
        atomicAdd(&out[threadIdx.x], t);
    }
}

extern "C" void kernel_launch(void* const* d_in, const int* in_sizes, int n_in,
                              void* d_out, int out_size, void* d_ws, size_t ws_size,
                              hipStream_t stream) {
    const int*   elm    = (const int*)d_in[0];
    const int*   edge_n = (const int*)d_in[1];
    const int*   edge_i = (const int*)d_in[2];
    const int*   edge_j = (const int*)d_in[3];
    const float* sod    = (const float*)d_in[4];
    const float* kparam = (const float*)d_in[5];
    const float* radius = (const float*)d_in[6];
    float* out = (float*)d_out;
    const int nE = in_sizes[1];

    (void)d_ws; (void)ws_size;  // workspace intentionally unused (R5 experiment)

    hipMemsetAsync(out, 0, out_size * sizeof(float), stream);
    // 512 blocks x 1024 thr: 2 blocks/CU resident, 32 waves/CU (R4 champion)
    hipLaunchKernelGGL(edge_kernel, dim3(512), dim3(1024), 0, stream,
                       elm, kparam, radius, edge_n, edge_i, edge_j, sod,
                       out, nE);
}

// Round 2
// 120.205 us; speedup vs baseline: 1.0553x; 1.0553x over previous
//
#include <hip/hip_runtime.h>
#include <hip/hip_bf16.h>
#include <hip/hip_fp16.h>

#define N_BCH 8
#define N_ATM 10000
#define N_ELM 100
#define N_ATOMS_TOT 80000

typedef int   i4 __attribute__((ext_vector_type(4)));
typedef float f4 __attribute__((ext_vector_type(4)));

// R6: revert to R4 champion structure (pack prepass + ws; fills proved
// unconditional in R5, and fused staging cost +8us). New change: unroll the
// grid-stride loop 2x — issue BOTH load-sets (8x16B in flight) before
// processing either, to double MLP. Theory: edge_kernel (~35us vs 13us BW
// floor) is memory-latency-exposed (only ~2.4 iters/thread, L3 flushed by
// harness fills each iteration -> every stream load is a ~900cy HBM miss).
// FP accumulation order unchanged (v=tid, then tid+stride, then tid+2*stride)
// -> absmax stays 0.

// Pre-pass: pack elm (int32, values <100) into u8 table in ws (80000 B).
__launch_bounds__(256)
__global__ void pack_elm_kernel(const int* __restrict__ elm,
                                unsigned int* __restrict__ elm_u8) {
    int t = blockIdx.x * blockDim.x + threadIdx.x;
    if (t < N_ATOMS_TOT / 4) {
        i4 v = *(const i4*)(elm + 4 * t);
        elm_u8[t] = (unsigned int)(v[0] & 0xff)
                  | ((unsigned int)(v[1] & 0xff) << 8)
                  | ((unsigned int)(v[2] & 0xff) << 16)
                  | ((unsigned int)(v[3] & 0xff) << 24);
    }
}

// R4 champion structure: all divergent accesses in LDS, grid-stride main loop.
//   s_elm32 : 80000 B u8 element types (whole batch)
//   s_kr    : 100x half2(k,r) -> one ds_read_b32 per endpoint
// LDS ~79.1 KiB -> 2 blocks/CU x 1024 thr = 32 waves/CU.
__launch_bounds__(1024, 8)
__global__ void edge_kernel(const unsigned int* __restrict__ elm_u8,
                            const float* __restrict__ kparam,
                            const float* __restrict__ radius,
                            const int* __restrict__ edge_n,
                            const int* __restrict__ edge_i,
                            const int* __restrict__ edge_j,
                            const float* __restrict__ sod,
                            float* __restrict__ out,
                            int nE) {
    __shared__ unsigned int s_elm32[N_ATOMS_TOT / 4];  // 80000 B
    __shared__ __half2 s_kr[128];                      // 512 B (100 used)
    __shared__ float s_red[16][N_BCH];                 // 512 B

    // ---- stage elm table (int4-vectorized: 5000 x 16B) + kr half2 table ----
    {
        const i4* src = (const i4*)elm_u8;
        i4* dst = (i4*)s_elm32;
        for (int t = threadIdx.x; t < N_ATOMS_TOT / 16; t += 1024)
            dst[t] = src[t];
        if (threadIdx.x < N_ELM)
            s_kr[threadIdx.x] =
                __floats2half2_rn(kparam[threadIdx.x], radius[threadIdx.x]);
    }
    __syncthreads();

    const unsigned char* s_elm = (const unsigned char*)s_elm32;

    float acc[N_BCH];
#pragma unroll
    for (int b = 0; b < N_BCH; ++b) acc[b] = 0.0f;

    const int tid    = blockIdx.x * blockDim.x + threadIdx.x;
    const int stride = gridDim.x * blockDim.x;
    const int nvec   = nE >> 2;

    const i4* en4 = (const i4*)edge_n;
    const i4* ei4 = (const i4*)edge_i;
    const i4* ej4 = (const i4*)edge_j;
    const f4* s4  = (const f4*)sod;

    // ---- unroll-2 grid-stride: 8 stream-loads in flight per wave ----
    int v = tid;
    for (; v + stride < nvec; v += 2 * stride) {
        const int w = v + stride;
        i4 nn0 = en4[v];   i4 ii0 = ei4[v];
        i4 jj0 = ej4[v];   f4 ss0 = s4[v];
        i4 nn1 = en4[w];   i4 ii1 = ei4[w];
        i4 jj1 = ej4[w];   f4 ss1 = s4[w];

#pragma unroll
        for (int u = 0; u < 4; ++u) {
            int n = nn0[u];
            int base = n * N_ATM;
            int e_i = s_elm[base + ii0[u]];
            int e_j = s_elm[base + jj0[u]];
            __half2 krsum = __hadd2(s_kr[e_i], s_kr[e_j]);
            float kk = __low2float(krsum);
            float R  = __high2float(krsum);
            float dis = sqrtf(ss0[u]);
            float d   = fminf(dis - R, 0.0f);   // ==0 unless dis<R (exact)
            float val = kk * d * d;
#pragma unroll
            for (int b = 0; b < N_BCH; ++b)
                acc[b] += (n == b) ? val : 0.0f;
        }
#pragma unroll
        for (int u = 0; u < 4; ++u) {
            int n = nn1[u];
            int base = n * N_ATM;
            int e_i = s_elm[base + ii1[u]];
            int e_j = s_elm[base + jj1[u]];
            __half2 krsum = __hadd2(s_kr[e_i], s_kr[e_j]);
            float kk = __low2float(krsum);
            float R  = __high2float(krsum);
            float dis = sqrtf(ss1[u]);
            float d   = fminf(dis - R, 0.0f);
            float val = kk * d * d;
#pragma unroll
            for (int b = 0; b < N_BCH; ++b)
                acc[b] += (n == b) ? val : 0.0f;
        }
    }
    // leftover single vec-iteration (same position in FP order as before)
    if (v < nvec) {
        i4 nn = en4[v];
        i4 ii = ei4[v];
        i4 jj = ej4[v];
        f4 ss = s4[v];
#pragma unroll
        for (int u = 0; u < 4; ++u) {
            int n = nn[u];
            int base = n * N_ATM;
            int e_i = s_elm[base + ii[u]];
            int e_j = s_elm[base + jj[u]];
            __half2 krsum = __hadd2(s_kr[e_i], s_kr[e_j]);
            float kk = __low2float(krsum);
            float R  = __high2float(krsum);
            float dis = sqrtf(ss[u]);
            float d   = fminf(dis - R, 0.0f);
            float val = kk * d * d;
#pragma unroll
            for (int b = 0; b < N_BCH; ++b)
                acc[b] += (n == b) ? val : 0.0f;
        }
    }

    // scalar tail (nE % 4)
    const int nvec2 = nvec;
    const int tail_start = nvec2 << 2;
    const int tail_n = nE - tail_start;
    if (tid < tail_n) {
        int e = tail_start + tid;
        int n = edge_n[e];
        int e_i = s_elm[n * N_ATM + edge_i[e]];
        int e_j = s_elm[n * N_ATM + edge_j[e]];
        __half2 krsum = __hadd2(s_kr[e_i], s_kr[e_j]);
        float kk = __low2float(krsum);
        float R  = __high2float(krsum);
        float dis = sqrtf(sod[e]);
        float d   = fminf(dis - R, 0.0f);
        float val = kk * d * d;
#pragma unroll
        for (int b = 0; b < N_BCH; ++b)
            acc[b] += (n == b) ? val : 0.0f;
    }

    // ---- two-phase wave reduction ----
    const int lane = threadIdx.x & 63;
    const int wave = threadIdx.x >> 6;   // 16 waves
#pragma unroll
    for (int off = 8; off <= 32; off <<= 1) {
#pragma unroll
        for (int b = 0; b < N_BCH; ++b)
            acc[b] += __shfl_xor(acc[b], off, 64);
    }
    const int j = lane >> 3;
    float x = acc[0];
#pragma unroll
    for (int b = 1; b < N_BCH; ++b) x = (j == b) ? acc[b] : x;
#pragma unroll
    for (int off = 1; off <= 4; off <<= 1)
        x += __shfl_xor(x, off, 64);

    if ((lane & 7) == 0) s_red[wave][j] = x;
    __syncthreads();
    if (threadIdx.x < N_BCH) {
        float t = 0.0f;
#pragma unroll
        for (int w = 0; w < 16; ++w) t += s_red[w][threadIdx.x];
        atomicAdd(&out[threadIdx.x], t);
    }
}

extern "C" void kernel_launch(void* const* d_in, const int* in_sizes, int n_in,
                              void* d_out, int out_size, void* d_ws, size_t ws_size,
                              hipStream_t stream) {
    const int*   elm    = (const int*)d_in[0];
    const int*   edge_n = (const int*)d_in[1];
    const int*   edge_i = (const int*)d_in[2];
    const int*   edge_j = (const int*)d_in[3];
    const float* sod    = (const float*)d_in[4];
    const float* kparam = (const float*)d_in[5];
    const float* radius = (const float*)d_in[6];
    float* out = (float*)d_out;
    const int nE = in_sizes[1];

    unsigned int* elm_u8 = (unsigned int*)d_ws;  // 80000 B packed u8 table

    hipMemsetAsync(out, 0, out_size * sizeof(float), stream);
    hipLaunchKernelGGL(pack_elm_kernel, dim3((N_ATOMS_TOT / 4 + 255) / 256),
                       dim3(256), 0, stream, elm, elm_u8);
    // 512 blocks x 1024 thr: 2 blocks/CU resident, 32 waves/CU (R4 champion)
    hipLaunchKernelGGL(edge_kernel, dim3(512), dim3(1024), 0, stream,
                       elm_u8, kparam, radius, edge_n, edge_i, edge_j, sod,
                       out, nE);
}

// Round 3
// 116.882 us; speedup vs baseline: 1.0853x; 1.0284x over previous
//
#include <hip/hip_runtime.h>
#include <hip/hip_bf16.h>
#include <hip/hip_fp16.h>

#define N_BCH 8
#define N_ATM 10000
#define N_ELM 100
#define N_ATOMS_TOT 80000

typedef int   i4 __attribute__((ext_vector_type(4)));
typedef float f4 __attribute__((ext_vector_type(4)));

// R7: R4 champion structure + two changes:
//  (1) register-tight 2-deep software pipeline in the grid-stride loop
//      (single PROCESS body, prefetch-next-then-rotate; peak live ~55 VGPR
//      so the __launch_bounds__(1024,8) <=64-VGPR envelope holds — R6's
//      dual-body unroll likely spilled, invalidating that test of the
//      latency theory).
//  (2) out[] zeroing folded into pack_elm_kernel -> hipMemsetAsync dispatch
//      removed (3 graph nodes -> 2).
// FP accumulation order identical to R4 (v, v+stride, ... per thread).

// Pre-pass: pack elm (int32, values <100) into u8 table in ws (80000 B).
// Also zeroes the 8-float output (replaces the memset dispatch; same-stream
// ordering guarantees completion before edge_kernel's atomics).
__launch_bounds__(256)
__global__ void pack_elm_kernel(const int* __restrict__ elm,
                                unsigned int* __restrict__ elm_u8,
                                float* __restrict__ out) {
    int t = blockIdx.x * blockDim.x + threadIdx.x;
    if (t < N_ATOMS_TOT / 4) {
        i4 v = *(const i4*)(elm + 4 * t);
        elm_u8[t] = (unsigned int)(v[0] & 0xff)
                  | ((unsigned int)(v[1] & 0xff) << 8)
                  | ((unsigned int)(v[2] & 0xff) << 16)
                  | ((unsigned int)(v[3] & 0xff) << 24);
    }
    if (blockIdx.x == 0 && threadIdx.x < N_BCH)
        out[threadIdx.x] = 0.0f;
}

// R4 champion structure: all divergent accesses in LDS, grid-stride main loop.
//   s_elm32 : 80000 B u8 element types (whole batch)
//   s_kr    : 100x half2(k,r) -> one ds_read_b32 per endpoint
// LDS ~79.1 KiB -> 2 blocks/CU x 1024 thr = 32 waves/CU.
__launch_bounds__(1024, 8)
__global__ void edge_kernel(const unsigned int* __restrict__ elm_u8,
                            const float* __restrict__ kparam,
                            const float* __restrict__ radius,
                            const int* __restrict__ edge_n,
                            const int* __restrict__ edge_i,
                            const int* __restrict__ edge_j,
                            const float* __restrict__ sod,
                            float* __restrict__ out,
                            int nE) {
    __shared__ unsigned int s_elm32[N_ATOMS_TOT / 4];  // 80000 B
    __shared__ __half2 s_kr[128];                      // 512 B (100 used)
    __shared__ float s_red[16][N_BCH];                 // 512 B

    // ---- stage elm table (int4-vectorized: 5000 x 16B) + kr half2 table ----
    {
        const i4* src = (const i4*)elm_u8;
        i4* dst = (i4*)s_elm32;
        for (int t = threadIdx.x; t < N_ATOMS_TOT / 16; t += 1024)
            dst[t] = src[t];
        if (threadIdx.x < N_ELM)
            s_kr[threadIdx.x] =
                __floats2half2_rn(kparam[threadIdx.x], radius[threadIdx.x]);
    }
    __syncthreads();

    const unsigned char* s_elm = (const unsigned char*)s_elm32;

    float acc[N_BCH];
#pragma unroll
    for (int b = 0; b < N_BCH; ++b) acc[b] = 0.0f;

    const int tid    = blockIdx.x * blockDim.x + threadIdx.x;
    const int stride = gridDim.x * blockDim.x;
    const int nvec   = nE >> 2;

    const i4* en4 = (const i4*)edge_n;
    const i4* ei4 = (const i4*)edge_i;
    const i4* ej4 = (const i4*)edge_j;
    const f4* s4  = (const f4*)sod;

#define PROCESS(nn, ii, jj, ss)                                         \
    do {                                                                \
        _Pragma("unroll")                                               \
        for (int u = 0; u < 4; ++u) {                                   \
            int n = (nn)[u];                                            \
            int base = n * N_ATM;                                       \
            int e_i = s_elm[base + (ii)[u]];                            \
            int e_j = s_elm[base + (jj)[u]];                            \
            __half2 krsum = __hadd2(s_kr[e_i], s_kr[e_j]);              \
            float kk = __low2float(krsum);                              \
            float R  = __high2float(krsum);                             \
            float dis = sqrtf((ss)[u]);                                 \
            float d   = fminf(dis - R, 0.0f);                           \
            float val = kk * d * d;                                     \
            _Pragma("unroll")                                           \
            for (int b = 0; b < N_BCH; ++b)                             \
                acc[b] += (n == b) ? val : 0.0f;                        \
        }                                                               \
    } while (0)

    // ---- 2-deep software-pipelined grid-stride loop ----
    int v = tid;
    if (v < nvec) {
        i4 nnA = en4[v];  i4 iiA = ei4[v];
        i4 jjA = ej4[v];  f4 ssA = s4[v];
        int w = v + stride;
        while (w < nvec) {
            i4 nnB = en4[w];  i4 iiB = ei4[w];   // prefetch next
            i4 jjB = ej4[w];  f4 ssB = s4[w];
            PROCESS(nnA, iiA, jjA, ssA);
            nnA = nnB; iiA = iiB; jjA = jjB; ssA = ssB;
            w += stride;
        }
        PROCESS(nnA, iiA, jjA, ssA);
    }

    // scalar tail (nE % 4)
    const int tail_start = nvec << 2;
    const int tail_n = nE - tail_start;
    if (tid < tail_n) {
        int e = tail_start + tid;
        int n = edge_n[e];
        int e_i = s_elm[n * N_ATM + edge_i[e]];
        int e_j = s_elm[n * N_ATM + edge_j[e]];
        __half2 krsum = __hadd2(s_kr[e_i], s_kr[e_j]);
        float kk = __low2float(krsum);
        float R  = __high2float(krsum);
        float dis = sqrtf(sod[e]);
        float d   = fminf(dis - R, 0.0f);
        float val = kk * d * d;
#pragma unroll
        for (int b = 0; b < N_BCH; ++b)
            acc[b] += (n == b) ? val : 0.0f;
    }

#undef PROCESS

    // ---- two-phase wave reduction ----
    const int lane = threadIdx.x & 63;
    const int wave = threadIdx.x >> 6;   // 16 waves
#pragma unroll
    for (int off = 8; off <= 32; off <<= 1) {
#pragma unroll
        for (int b = 0; b < N_BCH; ++b)
            acc[b] += __shfl_xor(acc[b], off, 64);
    }
    const int j = lane >> 3;
    float x = acc[0];
#pragma unroll
    for (int b = 1; b < N_BCH; ++b) x = (j == b) ? acc[b] : x;
#pragma unroll
    for (int off = 1; off <= 4; off <<= 1)
        x += __shfl_xor(x, off, 64);

    if ((lane & 7) == 0) s_red[wave][j] = x;
    __syncthreads();
    if (threadIdx.x < N_BCH) {
        float t = 0.0f;
#pragma unroll
        for (int w = 0; w < 16; ++w) t += s_red[w][threadIdx.x];
        atomicAdd(&out[threadIdx.x], t);
    }
}

extern "C" void kernel_launch(void* const* d_in, const int* in_sizes, int n_in,
                              void* d_out, int out_size, void* d_ws, size_t ws_size,
                              hipStream_t stream) {
    const int*   elm    = (const int*)d_in[0];
    const int*   edge_n = (const int*)d_in[1];
    const int*   edge_i = (const int*)d_in[2];
    const int*   edge_j = (const int*)d_in[3];
    const float* sod    = (const float*)d_in[4];
    const float* kparam = (const float*)d_in[5];
    const float* radius = (const float*)d_in[6];
    float* out = (float*)d_out;
    const int nE = in_sizes[1];

    unsigned int* elm_u8 = (unsigned int*)d_ws;  // 80000 B packed u8 table

    // pack kernel also zeroes out[] -> no memset dispatch (3 nodes -> 2)
    hipLaunchKernelGGL(pack_elm_kernel, dim3((N_ATOMS_TOT / 4 + 255) / 256),
                       dim3(256), 0, stream, elm, elm_u8, out);
    // 512 blocks x 1024 thr: 2 blocks/CU resident, 32 waves/CU (R4 champion)
    hipLaunchKernelGGL(edge_kernel, dim3(512), dim3(1024), 0, stream,
                       elm_u8, kparam, radius, edge_n, edge_i, edge_j, sod,
                       out, nE);
}